// Round 6
// baseline (586.253 us; speedup 1.0000x reference)
//
#include <hip/hip_runtime.h>
#include <hip/hip_bf16.h>

// NodeModelBase: per-edge MLP (Linear->LN->ReLU->Linear) + scatter_mean.
// Strategy: bf16 MFMA (16x16x32), swapped orientation D[n][e] = W^T * feat.
// R6: SINGLE-DISPATCH pipeline. hist -> two-level scan -> scatter -> mlp all
//     in one kernel, separated by device-scope atomic grid barriers.
//     Safe: LDS ~100KB forces 1 block/CU; grid = min(256, #CU) blocks -> all
//     co-resident, one-shot arrive+spin barriers cannot deadlock. Barrier
//     slots zeroed per iteration by the captured memset. The non-mlp residual
//     has been a constant ~335-395us across R0-R5 while every kernel change
//     moved only its own phase; this either removes it (dispatch-bound) or
//     proves it's harness-fixed.
//     Kept from R4/R5: W1/W2 stream from LDS frag-major (register-resident
//     weights spill at 2 waves/SIMD), 512-thr blocks, 2-deep gather pipeline,
//     fused segmented-mean epilogue (atomics, ~2 segs/tile).

typedef __bf16 bf16x8 __attribute__((ext_vector_type(8)));
typedef float f32x4 __attribute__((ext_vector_type(4)));

#define LN_EPS 1e-5f

__device__ __forceinline__ unsigned short bfbits(float f) {
  return __builtin_bit_cast(unsigned short, (__bf16)f);
}
__device__ __forceinline__ float bflo(unsigned int u) { return __uint_as_float(u << 16); }
__device__ __forceinline__ float bfhi(unsigned int u) { return __uint_as_float(u & 0xffff0000u); }
__device__ __forceinline__ unsigned int pkbf(float a, float b) {
  return (unsigned int)bfbits(a) | ((unsigned int)bfbits(b) << 16);
}

// one-shot grid barrier (slot pre-zeroed host-side each launch).
// Requires all gridDim.x blocks co-resident (guaranteed: 1 block/CU by LDS,
// grid <= #CU). Release/acquire at agent scope handles cross-XCD visibility.
__device__ __forceinline__ void gbar(int* slot) {
  __syncthreads();
  if (threadIdx.x == 0) {
    __threadfence();
    __hip_atomic_fetch_add(slot, 1, __ATOMIC_ACQ_REL, __HIP_MEMORY_SCOPE_AGENT);
    while (__hip_atomic_load(slot, __ATOMIC_ACQUIRE, __HIP_MEMORY_SCOPE_AGENT) <
           (int)gridDim.x)
      __builtin_amdgcn_s_sleep(2);
  }
  __syncthreads();
}

// ---------------------------------------------------- fallback-path helpers
__global__ void hist_kernel(const int* __restrict__ eidx, int* __restrict__ cnt, int E) {
  int e = blockIdx.x * blockDim.x + threadIdx.x;
  if (e < E) atomicAdd(&cnt[eidx[E + e]], 1);
}

__global__ void divide_kernel(float* __restrict__ out, const int* __restrict__ cnt, int N) {
  int i = blockIdx.x * blockDim.x + threadIdx.x;
  if (i >= N * 32) return;  // N*128/4 float4s
  int node = i >> 5;
  float s = 1.f / (float)(cnt[node] > 0 ? cnt[node] : 1);
  float4* p = (float4*)out + i;
  float4 v = *p;
  v.x *= s;
  v.y *= s;
  v.z *= s;
  v.w *= s;
  *p = v;
}

// ------------------------------------------------------- fused main kernel
// FUSED=true : hist -> scan -> scatter -> CSR mlp + segmented-mean epilogue
// FUSED=false: per-edge atomic scatter path (no barriers; divide_kernel after)
template <bool FUSED>
__global__ __launch_bounds__(512, 2) void mlp_kernel(
    const float* __restrict__ x, const float* __restrict__ ea,
    const int* __restrict__ eidx, int* __restrict__ perm,
    int* __restrict__ rowp, int* __restrict__ cnt, int* __restrict__ cur,
    int* __restrict__ off, int* __restrict__ blkSum, int* __restrict__ blkOff,
    int* __restrict__ bar, const float* __restrict__ W1,
    const float* __restrict__ b1, const float* __restrict__ lng,
    const float* __restrict__ lnb, const float* __restrict__ W2,
    const float* __restrict__ b2, float* __restrict__ out, int N, int E,
    int ntiles) {
  // weights bf16 frag-major: chunk c = fragid*64 + lane, 16 B each -> 32 KB ea.
  __shared__ __align__(16) unsigned int w1L[2048 * 4];
  __shared__ __align__(16) unsigned int w2L[2048 * 4];
  __shared__ float b1L[128];
  __shared__ float b2L[128];
  __shared__ unsigned int glcL[128];  // low16 = bf16(ln_g), high16 = bf16(ln_b)
  // 16 rows * 272B (128 bf16 + 8 pad, keeps 16B alignment, breaks bank strides)
  __shared__ __align__(16) char hbuf[8][16 * 272];
  __shared__ int wsumS[8];

  const int tid = threadIdx.x;
  const int lane = tid & 63;
  const int wv = tid >> 6;
  const int ln = lane;
  const int e15 = lane & 15;
  const int q = lane >> 4;
  char* hb = hbuf[wv];

  // ---- stage W1/W2 into LDS as MFMA A-fragments (bf16, frag-major) ----
  // Lane l of frag (ks,mt) holds W[k=ks*32+(l>>4)*8+j][n=mt*16+(l&15)], j=0..7
  for (int c = tid; c < 2048; c += 512) {
    const int fragid = c >> 6;
    const int l = c & 63;
    const int ks = fragid >> 3, mt = fragid & 7;
    const int qq = l >> 4, ee = l & 15;
    const size_t base = (size_t)(ks * 32 + qq * 8) * 128 + mt * 16 + ee;
    unsigned int p1[4], p2[4];
#pragma unroll
    for (int jj = 0; jj < 4; ++jj) {
      p1[jj] = pkbf(W1[base + (size_t)(2 * jj) * 128], W1[base + (size_t)(2 * jj + 1) * 128]);
      p2[jj] = pkbf(W2[base + (size_t)(2 * jj) * 128], W2[base + (size_t)(2 * jj + 1) * 128]);
    }
    uint4 v1 = {p1[0], p1[1], p1[2], p1[3]};
    uint4 v2 = {p2[0], p2[1], p2[2], p2[3]};
    *(uint4*)&w1L[c * 4] = v1;
    *(uint4*)&w2L[c * 4] = v2;
  }
  if (tid < 128) {
    b1L[tid] = b1[tid];
    b2L[tid] = b2[tid];
    glcL[tid] = pkbf(lng[tid], lnb[tid]);
  }

  const int nb = gridDim.x;
  const int gthreads = nb * 512;
  const int gtid = blockIdx.x * 512 + tid;

  if constexpr (FUSED) {
    // ---- phase 1: histogram ----
    for (int e = gtid; e < E; e += gthreads) atomicAdd(&cnt[eidx[E + e]], 1);
    gbar(&bar[0]);

    // ---- phase 2a: block-local exclusive scan of cnt chunk ----
    const int CHUNK = (N + nb - 1) / nb;  // 196 at N=50000, nb=256 (<=512)
    const int base = blockIdx.x * CHUNK;
    const int myi = base + tid;
    int v = 0;
    if (tid < CHUNK && myi < N) v = cnt[myi];
    int sc = v;
#pragma unroll
    for (int d = 1; d < 64; d <<= 1) {
      int t = __shfl_up(sc, d);
      if (ln >= d) sc += t;
    }
    if (ln == 63) wsumS[wv] = sc;
    __syncthreads();
    int woff = 0;
#pragma unroll
    for (int w = 0; w < 8; ++w) {
      int t = wsumS[w];
      if (w < wv) woff += t;
    }
    const int excl = woff + sc - v;  // block-local exclusive prefix
    if (tid == 0) {
      int s = 0;
#pragma unroll
      for (int w = 0; w < 8; ++w) s += wsumS[w];
      blkSum[blockIdx.x] = s;
    }
    gbar(&bar[1]);

    // ---- phase 2b: block 0 scans the block sums ----
    if (blockIdx.x == 0) {
      int v2 = (tid < nb) ? blkSum[tid] : 0;
      int sc2 = v2;
#pragma unroll
      for (int d = 1; d < 64; d <<= 1) {
        int t = __shfl_up(sc2, d);
        if (ln >= d) sc2 += t;
      }
      __syncthreads();  // previous wsumS uses complete
      if (ln == 63) wsumS[wv] = sc2;
      __syncthreads();
      int woff2 = 0;
#pragma unroll
      for (int w = 0; w < 8; ++w) {
        int t = wsumS[w];
        if (w < wv) woff2 += t;
      }
      if (tid < nb) blkOff[tid] = woff2 + sc2 - v2;
    }
    gbar(&bar[2]);

    // ---- phase 2c: global offsets ----
    const int boff = blkOff[blockIdx.x];
    if (tid < CHUNK && myi < N) off[myi] = excl + boff;
    gbar(&bar[3]);

    // ---- phase 3: bucket scatter (CSR perm + source-row lookup) ----
    for (int e = gtid; e < E; e += gthreads) {
      int c = eidx[E + e];
      int p = atomicAdd(&cur[c], 1);
      int pos = off[c] + p;
      perm[pos] = e;
      rowp[pos] = eidx[e];
    }
    gbar(&bar[4]);
  } else {
    __syncthreads();  // weight staging visible
  }

  const int nwav = gthreads >> 6;
  const int wid = gtid >> 6;

  // per-tile MLP core: raw f32 features -> c2 (GEMM1 -> LN -> ReLU -> GEMM2)
  auto mlp_core = [&](const float4 (&raw)[8], f32x4 (&c2)[8]) {
    bf16x8 bfr[4];
#pragma unroll
    for (int ks = 0; ks < 4; ++ks) {
      const float* p0 = (const float*)&raw[2 * ks];
      const float* p1 = (const float*)&raw[2 * ks + 1];
#pragma unroll
      for (int j = 0; j < 4; ++j) {
        bfr[ks][j] = (__bf16)p0[j];
        bfr[ks][4 + j] = (__bf16)p1[j];
      }
    }
    f32x4 c1[8];
#pragma unroll
    for (int mt = 0; mt < 8; ++mt) {
      float4 bv = *(const float4*)&b1L[mt * 16 + q * 4];
      c1[mt][0] = bv.x;
      c1[mt][1] = bv.y;
      c1[mt][2] = bv.z;
      c1[mt][3] = bv.w;
    }
#pragma unroll
    for (int ks = 0; ks < 4; ++ks)
#pragma unroll
      for (int mt = 0; mt < 8; ++mt) {
        bf16x8 wf = __builtin_bit_cast(
            bf16x8, *(const uint4*)&w1L[((ks * 8 + mt) * 64 + lane) * 4]);
        c1[mt] = __builtin_amdgcn_mfma_f32_16x16x32_bf16(wf, bfr[ks], c1[mt], 0, 0, 0);
      }

    // LayerNorm over 128 features of this edge (lanes e15, +16, +32, +48)
    float s = 0.f, ss = 0.f;
#pragma unroll
    for (int mt = 0; mt < 8; ++mt)
#pragma unroll
      for (int r = 0; r < 4; ++r) {
        float v = c1[mt][r];
        s += v;
        ss += v * v;
      }
    s += __shfl_xor(s, 16);
    s += __shfl_xor(s, 32);
    ss += __shfl_xor(ss, 16);
    ss += __shfl_xor(ss, 32);
    const float mu = s * 0.0078125f;
    const float var = ss * 0.0078125f - mu * mu;
    const float inv = rsqrtf(var + LN_EPS);
#pragma unroll
    for (int mt = 0; mt < 8; ++mt) {
      uint4 gv = *(const uint4*)&glcL[mt * 16 + q * 4];
      unsigned int g[4] = {gv.x, gv.y, gv.z, gv.w};
      unsigned short u[4];
#pragma unroll
      for (int r = 0; r < 4; ++r) {
        float v = (c1[mt][r] - mu) * inv;
        v = v * bflo(g[r]) + bfhi(g[r]);
        v = fmaxf(v, 0.f);
        u[r] = bfbits(v);
      }
      uint2 w;
      w.x = (unsigned int)u[0] | ((unsigned int)u[1] << 16);
      w.y = (unsigned int)u[2] | ((unsigned int)u[3] << 16);
      *(uint2*)(hb + e15 * 272 + mt * 32 + q * 8) = w;
    }
    bf16x8 hf[4];
#pragma unroll
    for (int ks = 0; ks < 4; ++ks)
      hf[ks] = __builtin_bit_cast(bf16x8, *(const uint4*)(hb + e15 * 272 + ks * 64 + q * 16));
#pragma unroll
    for (int mt = 0; mt < 8; ++mt) {
      float4 bv = *(const float4*)&b2L[mt * 16 + q * 4];
      c2[mt][0] = bv.x;
      c2[mt][1] = bv.y;
      c2[mt][2] = bv.z;
      c2[mt][3] = bv.w;
    }
#pragma unroll
    for (int ks = 0; ks < 4; ++ks)
#pragma unroll
      for (int mt = 0; mt < 8; ++mt) {
        bf16x8 wf = __builtin_bit_cast(
            bf16x8, *(const uint4*)&w2L[((ks * 8 + mt) * 64 + lane) * 4]);
        c2[mt] = __builtin_amdgcn_mfma_f32_16x16x32_bf16(wf, hf[ks], c2[mt], 0, 0, 0);
      }
  };

  // Fused segmented-mean epilogue: stage tile's 16 bf16 rows in LDS, then
  // run-length segment the 16 CSR positions by dest node (wave-uniform via
  // shfl from lanes 0-15) and atomically add seg_sum/deg into out.
  auto reduce_store = [&](const f32x4 (&c2)[8], int nd, float inv) {
#pragma unroll
    for (int mt = 0; mt < 8; ++mt) {
      unsigned short u[4];
#pragma unroll
      for (int r = 0; r < 4; ++r) u[r] = bfbits(c2[mt][r]);
      uint2 w;
      w.x = (unsigned int)u[0] | ((unsigned int)u[1] << 16);
      w.y = (unsigned int)u[2] | ((unsigned int)u[3] << 16);
      *(uint2*)(hb + e15 * 272 + mt * 32 + q * 8) = w;
    }
    float acc0 = 0.f, acc1 = 0.f;
    int curn = __shfl(nd, 0);
    float cinv = __shfl(inv, 0);
#pragma unroll
    for (int i = 0; i < 16; ++i) {
      int ni = __shfl(nd, i);
      float ii = __shfl(inv, i);
      if (ni != curn) {  // wave-uniform branch
        unsafeAtomicAdd(out + (size_t)curn * 128 + lane * 2, acc0 * cinv);
        unsafeAtomicAdd(out + (size_t)curn * 128 + lane * 2 + 1, acc1 * cinv);
        acc0 = 0.f;
        acc1 = 0.f;
        curn = ni;
        cinv = ii;
      }
      unsigned int v = *(const unsigned int*)(hb + i * 272 + lane * 4);
      acc0 += bflo(v);
      acc1 += bfhi(v);
    }
    unsafeAtomicAdd(out + (size_t)curn * 128 + lane * 2, acc0 * cinv);
    unsafeAtomicAdd(out + (size_t)curn * 128 + lane * 2 + 1, acc1 * cinv);
  };

#define LOADRAW(dst, rowv, ev)                              \
  do {                                                      \
    const float* xr_ = x + (size_t)(rowv)*64;               \
    const float* ar_ = ea + (size_t)(ev)*64;                \
    dst[0] = *(const float4*)(xr_ + q * 8);                 \
    dst[1] = *(const float4*)(xr_ + q * 8 + 4);             \
    dst[2] = *(const float4*)(xr_ + 32 + q * 8);            \
    dst[3] = *(const float4*)(xr_ + 32 + q * 8 + 4);        \
    dst[4] = *(const float4*)(ar_ + q * 8);                 \
    dst[5] = *(const float4*)(ar_ + q * 8 + 4);             \
    dst[6] = *(const float4*)(ar_ + 32 + q * 8);            \
    dst[7] = *(const float4*)(ar_ + 32 + q * 8 + 4);        \
  } while (0)

  if constexpr (FUSED) {
    int tA = wid;
    if (tA >= ntiles) return;
    // prologue: idx/node/deg for tiles A and B, raw for tile A
    int pA = tA * 16 + e15;
    int eA = perm[pA];
    int rowA = rowp[pA];
    int ndA = eidx[E + eA];
    float invA = 1.f / (float)cnt[ndA];
    int tB = tA + nwav;
    int tBc = (tB < ntiles) ? tB : tA;
    int pB = tBc * 16 + e15;
    int eB = perm[pB];
    int rowB = rowp[pB];
    int ndB = eidx[E + eB];
    float invB = 1.f / (float)cnt[ndB];
    float4 rawA[8], rawB[8];
    LOADRAW(rawA, rowA, eA);

    for (int tb = tA; tb < ntiles; tb += 2 * nwav) {
      // ---- phase A: compute tile tb; prefetch rawB(tb+nwav), idxA(tb+2nwav)
      {
        int tn = tb + 2 * nwav;
        int tc = (tn < ntiles) ? tn : tb;
        int pn = tc * 16 + e15;
        int eAn = perm[pn];
        int rAn = rowp[pn];
        int nAn = eidx[E + eAn];
        float iAn = 1.f / (float)cnt[nAn];
        LOADRAW(rawB, rowB, eB);
        f32x4 c2[8];
        mlp_core(rawA, c2);
        reduce_store(c2, ndA, invA);
        eA = eAn;
        rowA = rAn;
        ndA = nAn;
        invA = iAn;
      }
      // ---- phase B: compute tile tb+nwav; prefetch rawA(tb+2nwav), idxB(tb+3nwav)
      {
        int tcur = tb + nwav;
        int tn = tb + 3 * nwav;
        int tc = (tn < ntiles) ? tn : tb;
        int pn = tc * 16 + e15;
        int eBn = perm[pn];
        int rBn = rowp[pn];
        int nBn = eidx[E + eBn];
        float iBn = 1.f / (float)cnt[nBn];
        LOADRAW(rawA, rowA, eA);
        if (tcur < ntiles) {
          f32x4 c2[8];
          mlp_core(rawB, c2);
          reduce_store(c2, ndB, invB);
        }
        eB = eBn;
        rowB = rBn;
        ndB = nBn;
        invB = iBn;
      }
    }
  } else {
    // fallback: fused atomic scatter of UNSCALED sums (divide_kernel follows)
    for (int t = wid; t < ntiles; t += nwav) {
      const int pos = t * 16 + e15;
      const int e = pos;
      const int row = eidx[e];
      const int cl = eidx[E + e];
      float4 raw[8];
      LOADRAW(raw, row, e);
      f32x4 c2[8];
      mlp_core(raw, c2);
      float* op = out + (size_t)cl * 128 + q * 4;
#pragma unroll
      for (int mt = 0; mt < 8; ++mt)
#pragma unroll
        for (int r = 0; r < 4; ++r) unsafeAtomicAdd(op + mt * 16 + r, c2[mt][r]);
    }
  }
#undef LOADRAW
}

extern "C" void kernel_launch(void* const* d_in, const int* in_sizes, int n_in,
                              void* d_out, int out_size, void* d_ws, size_t ws_size,
                              hipStream_t stream) {
  const float* x = (const float*)d_in[0];
  const float* ea = (const float*)d_in[1];
  const int* eidx = (const int*)d_in[2];
  const float* W1 = (const float*)d_in[3];
  const float* b1 = (const float*)d_in[4];
  const float* lng = (const float*)d_in[5];
  const float* lnb = (const float*)d_in[6];
  const float* W2 = (const float*)d_in[7];
  const float* b2 = (const float*)d_in[8];
  float* out = (float*)d_out;

  const int N = in_sizes[0] / 64;   // 50000
  const int E = in_sizes[1] / 64;   // 800000
  const int ntiles = E / 16;
  const size_t permB = (size_t)E * 4;
  const size_t cB = (size_t)N * 4;
  // ws: perm[E] rowp[E] | cnt[N] cur[N] off[N] blkSum[256] blkOff[256] bar[16]
  const size_t tailI = 3 * (size_t)N + 512 + 16;
  const size_t need = 2 * permB + tailI * 4;

  static int nb_cached = 0;
  if (nb_cached == 0) {
    int dev = 0;
    hipGetDevice(&dev);
    hipDeviceProp_t prop;
    hipGetDeviceProperties(&prop, dev);
    nb_cached = prop.multiProcessorCount < 256 ? prop.multiProcessorCount : 256;
  }
  const int nb = nb_cached;

  if (ws_size >= need && nb >= 98 && (size_t)nb * 512 >= (size_t)512) {
    // ---- single-dispatch CSR + fused segmented-mean path ----
    int* perm = (int*)d_ws;
    int* rowp = perm + E;
    int* cnt = rowp + E;
    int* cur = cnt + N;
    int* off = cur + N;
    int* blkSum = off + N;
    int* blkOff = blkSum + 256;
    int* bar = blkOff + 256;
    hipMemsetAsync(out, 0, (size_t)out_size * 4, stream);
    hipMemsetAsync(cnt, 0, tailI * 4, stream);  // cnt,cur,off,blkSum/Off,bar
    mlp_kernel<true><<<nb, 512, 0, stream>>>(x, ea, eidx, perm, rowp, cnt, cur, off,
                                             blkSum, blkOff, bar, W1, b1, lng, lnb,
                                             W2, b2, out, N, E, ntiles);
  } else {
    // ---- fallback: fused atomic scatter (needs only N*4 bytes of ws) ----
    int* cnt = (int*)d_ws;
    const int eblocks = (E + 255) / 256;
    hipMemsetAsync(out, 0, (size_t)out_size * 4, stream);
    hipMemsetAsync(cnt, 0, cB, stream);
    hist_kernel<<<eblocks, 256, 0, stream>>>(eidx, cnt, E);
    mlp_kernel<false><<<256, 512, 0, stream>>>(x, ea, eidx, nullptr, nullptr, cnt,
                                               nullptr, nullptr, nullptr, nullptr,
                                               nullptr, W1, b1, lng, lnb, W2, b2,
                                               out, N, E, ntiles);
    divide_kernel<<<(N * 32 + 255) / 256, 256, 0, stream>>>(out, cnt, N);
  }
}

// Round 7
// 481.876 us; speedup vs baseline: 1.2166x; 1.2166x over previous
//
#include <hip/hip_runtime.h>
#include <hip/hip_bf16.h>

// NodeModelBase: per-edge MLP (Linear->LN->ReLU->Linear) + scatter_mean.
// Strategy: bf16 MFMA (16x16x32), swapped orientation D[n][e] = W^T * feat.
// R7: revert R6's single-dispatch fusion (preproc at 2 waves/SIMD + grid
//     barriers cost 227us vs ~90us as separate dispatches; residual ~200us
//     proved harness-fixed). Back to R5 structure with two changes:
//     (a) 1024-thread mlp blocks: LDS 133.5KB -> 1 block/CU = 4 waves/SIMD
//         (was 2). Same 128-VGPR cap as (512,2) -> no spill risk (kernel
//         compiles at 104).
//     (b) drop rowp: scatter writes only perm (halves its scattered RMW
//         traffic); mlp gathers eidx[e]/eidx[E+e] in the index-prefetch slot.
//     Kept: W1/W2 stream from LDS frag-major (register-resident weights
//     spill: R1/R3 1.46GB scratch FETCH), 2-deep gather pipeline, fused
//     segmented-mean epilogue (~2 segs/tile, ~51MB atomics).

typedef __bf16 bf16x8 __attribute__((ext_vector_type(8)));
typedef float f32x4 __attribute__((ext_vector_type(4)));

#define LN_EPS 1e-5f

__device__ __forceinline__ unsigned short bfbits(float f) {
  return __builtin_bit_cast(unsigned short, (__bf16)f);
}
__device__ __forceinline__ float bflo(unsigned int u) { return __uint_as_float(u << 16); }
__device__ __forceinline__ float bfhi(unsigned int u) { return __uint_as_float(u & 0xffff0000u); }
__device__ __forceinline__ unsigned int pkbf(float a, float b) {
  return (unsigned int)bfbits(a) | ((unsigned int)bfbits(b) << 16);
}

// ---------------------------------------------------------------- histogram
__global__ void hist_kernel(const int* __restrict__ eidx, int* __restrict__ cnt, int E) {
  int e = blockIdx.x * blockDim.x + threadIdx.x;
  if (e < E) atomicAdd(&cnt[eidx[E + e]], 1);
}

// ------------------------------------------------------- exclusive scan (1 WG)
__global__ void scan_kernel(const int* __restrict__ cnt, int* __restrict__ off, int n) {
  __shared__ int wsum[16];
  __shared__ int carry_s;
  const int tid = threadIdx.x;
  const int wv = tid >> 6;
  const int ln = tid & 63;
  if (tid == 0) carry_s = 0;
  __syncthreads();
  for (int base = 0; base < n; base += 4096) {
    int i0 = base + tid * 4;
    int a = (i0 < n) ? cnt[i0] : 0;
    int b = (i0 + 1 < n) ? cnt[i0 + 1] : 0;
    int c = (i0 + 2 < n) ? cnt[i0 + 2] : 0;
    int d = (i0 + 3 < n) ? cnt[i0 + 3] : 0;
    int lsum = a + b + c + d;
    int sc = lsum;
#pragma unroll
    for (int dl = 1; dl < 64; dl <<= 1) {
      int t = __shfl_up(sc, dl);
      if (ln >= dl) sc += t;
    }
    if (ln == 63) wsum[wv] = sc;
    __syncthreads();
    int woff = 0;
#pragma unroll
    for (int w = 0; w < 16; ++w) {
      int t = wsum[w];
      if (w < wv) woff += t;
    }
    int excl = carry_s + woff + sc - lsum;
    if (i0 < n) off[i0] = excl;
    if (i0 + 1 < n) off[i0 + 1] = excl + a;
    if (i0 + 2 < n) off[i0 + 2] = excl + a + b;
    if (i0 + 3 < n) off[i0 + 3] = excl + a + b + c;
    __syncthreads();
    if (tid == 1023) carry_s = carry_s + woff + sc;
    __syncthreads();
  }
}

// ------------------------------------------------------------ bucket scatter
__global__ void scatter_kernel(const int* __restrict__ eidx, const int* __restrict__ off,
                               int* __restrict__ cur, int* __restrict__ perm, int E) {
  int e = blockIdx.x * blockDim.x + threadIdx.x;
  if (e < E) {
    int c = eidx[E + e];
    int p = atomicAdd(&cur[c], 1);
    perm[off[c] + p] = e;
  }
}

// ----------------------------------------------------------------- main MLP
template <bool ATOMIC>
__global__ __launch_bounds__(1024, 1) void mlp_kernel(
    const float* __restrict__ x, const float* __restrict__ ea,
    const int* __restrict__ eidx, const int* __restrict__ perm,
    const int* __restrict__ cnt, const float* __restrict__ W1,
    const float* __restrict__ b1, const float* __restrict__ lng,
    const float* __restrict__ lnb, const float* __restrict__ W2,
    const float* __restrict__ b2, float* __restrict__ out, int E, int ntiles) {
  // weights bf16 frag-major: chunk c = fragid*64 + lane, 16 B each -> 32 KB ea.
  __shared__ __align__(16) unsigned int w1L[2048 * 4];
  __shared__ __align__(16) unsigned int w2L[2048 * 4];
  __shared__ float b1L[128];
  __shared__ float b2L[128];
  __shared__ unsigned int glcL[128];  // low16 = bf16(ln_g), high16 = bf16(ln_b)
  // 16 rows * 272B (128 bf16 + 8 pad, keeps 16B alignment, breaks bank strides)
  __shared__ __align__(16) char hbuf[16][16 * 272];

  const int tid = threadIdx.x;
  const int lane = tid & 63;
  const int wv = tid >> 6;
  const int e15 = lane & 15;
  const int q = lane >> 4;
  char* hb = hbuf[wv];

  // ---- stage W1/W2 into LDS as MFMA A-fragments (bf16, frag-major) ----
  // Lane l of frag (ks,mt) holds W[k=ks*32+(l>>4)*8+j][n=mt*16+(l&15)], j=0..7
  for (int c = tid; c < 2048; c += 1024) {
    const int fragid = c >> 6;
    const int l = c & 63;
    const int ks = fragid >> 3, mt = fragid & 7;
    const int qq = l >> 4, ee = l & 15;
    const size_t base = (size_t)(ks * 32 + qq * 8) * 128 + mt * 16 + ee;
    unsigned int p1[4], p2[4];
#pragma unroll
    for (int jj = 0; jj < 4; ++jj) {
      p1[jj] = pkbf(W1[base + (size_t)(2 * jj) * 128], W1[base + (size_t)(2 * jj + 1) * 128]);
      p2[jj] = pkbf(W2[base + (size_t)(2 * jj) * 128], W2[base + (size_t)(2 * jj + 1) * 128]);
    }
    uint4 v1 = {p1[0], p1[1], p1[2], p1[3]};
    uint4 v2 = {p2[0], p2[1], p2[2], p2[3]};
    *(uint4*)&w1L[c * 4] = v1;
    *(uint4*)&w2L[c * 4] = v2;
  }
  if (tid < 128) {
    b1L[tid] = b1[tid];
    b2L[tid] = b2[tid];
    glcL[tid] = pkbf(lng[tid], lnb[tid]);
  }
  __syncthreads();

  const int nwav = (gridDim.x * blockDim.x) >> 6;
  const int wid = (blockIdx.x * blockDim.x + tid) >> 6;

  // per-tile MLP core: raw f32 features -> c2 (GEMM1 -> LN -> ReLU -> GEMM2)
  auto mlp_core = [&](const float4 (&raw)[8], f32x4 (&c2)[8]) {
    bf16x8 bfr[4];
#pragma unroll
    for (int ks = 0; ks < 4; ++ks) {
      const float* p0 = (const float*)&raw[2 * ks];
      const float* p1 = (const float*)&raw[2 * ks + 1];
#pragma unroll
      for (int j = 0; j < 4; ++j) {
        bfr[ks][j] = (__bf16)p0[j];
        bfr[ks][4 + j] = (__bf16)p1[j];
      }
    }
    f32x4 c1[8];
#pragma unroll
    for (int mt = 0; mt < 8; ++mt) {
      float4 bv = *(const float4*)&b1L[mt * 16 + q * 4];
      c1[mt][0] = bv.x;
      c1[mt][1] = bv.y;
      c1[mt][2] = bv.z;
      c1[mt][3] = bv.w;
    }
#pragma unroll
    for (int ks = 0; ks < 4; ++ks)
#pragma unroll
      for (int mt = 0; mt < 8; ++mt) {
        bf16x8 wf = __builtin_bit_cast(
            bf16x8, *(const uint4*)&w1L[((ks * 8 + mt) * 64 + lane) * 4]);
        c1[mt] = __builtin_amdgcn_mfma_f32_16x16x32_bf16(wf, bfr[ks], c1[mt], 0, 0, 0);
      }

    // LayerNorm over 128 features of this edge (lanes e15, +16, +32, +48)
    float s = 0.f, ss = 0.f;
#pragma unroll
    for (int mt = 0; mt < 8; ++mt)
#pragma unroll
      for (int r = 0; r < 4; ++r) {
        float v = c1[mt][r];
        s += v;
        ss += v * v;
      }
    s += __shfl_xor(s, 16);
    s += __shfl_xor(s, 32);
    ss += __shfl_xor(ss, 16);
    ss += __shfl_xor(ss, 32);
    const float mu = s * 0.0078125f;
    const float var = ss * 0.0078125f - mu * mu;
    const float inv = rsqrtf(var + LN_EPS);
#pragma unroll
    for (int mt = 0; mt < 8; ++mt) {
      uint4 gv = *(const uint4*)&glcL[mt * 16 + q * 4];
      unsigned int g[4] = {gv.x, gv.y, gv.z, gv.w};
      unsigned short u[4];
#pragma unroll
      for (int r = 0; r < 4; ++r) {
        float v = (c1[mt][r] - mu) * inv;
        v = v * bflo(g[r]) + bfhi(g[r]);
        v = fmaxf(v, 0.f);
        u[r] = bfbits(v);
      }
      uint2 w;
      w.x = (unsigned int)u[0] | ((unsigned int)u[1] << 16);
      w.y = (unsigned int)u[2] | ((unsigned int)u[3] << 16);
      *(uint2*)(hb + e15 * 272 + mt * 32 + q * 8) = w;
    }
    bf16x8 hf[4];
#pragma unroll
    for (int ks = 0; ks < 4; ++ks)
      hf[ks] = __builtin_bit_cast(bf16x8, *(const uint4*)(hb + e15 * 272 + ks * 64 + q * 16));
#pragma unroll
    for (int mt = 0; mt < 8; ++mt) {
      float4 bv = *(const float4*)&b2L[mt * 16 + q * 4];
      c2[mt][0] = bv.x;
      c2[mt][1] = bv.y;
      c2[mt][2] = bv.z;
      c2[mt][3] = bv.w;
    }
#pragma unroll
    for (int ks = 0; ks < 4; ++ks)
#pragma unroll
      for (int mt = 0; mt < 8; ++mt) {
        bf16x8 wf = __builtin_bit_cast(
            bf16x8, *(const uint4*)&w2L[((ks * 8 + mt) * 64 + lane) * 4]);
        c2[mt] = __builtin_amdgcn_mfma_f32_16x16x32_bf16(wf, hf[ks], c2[mt], 0, 0, 0);
      }
  };

  // Fused segmented-mean epilogue: stage tile's 16 bf16 rows in LDS, then
  // run-length segment the 16 CSR positions by dest node (wave-uniform via
  // shfl from lanes 0-15) and atomically add seg_sum/deg into out.
  auto reduce_store = [&](const f32x4 (&c2)[8], int nd, float inv) {
#pragma unroll
    for (int mt = 0; mt < 8; ++mt) {
      unsigned short u[4];
#pragma unroll
      for (int r = 0; r < 4; ++r) u[r] = bfbits(c2[mt][r]);
      uint2 w;
      w.x = (unsigned int)u[0] | ((unsigned int)u[1] << 16);
      w.y = (unsigned int)u[2] | ((unsigned int)u[3] << 16);
      *(uint2*)(hb + e15 * 272 + mt * 32 + q * 8) = w;
    }
    float acc0 = 0.f, acc1 = 0.f;
    int curn = __shfl(nd, 0);
    float cinv = __shfl(inv, 0);
#pragma unroll
    for (int i = 0; i < 16; ++i) {
      int ni = __shfl(nd, i);
      float ii = __shfl(inv, i);
      if (ni != curn) {  // wave-uniform branch
        unsafeAtomicAdd(out + (size_t)curn * 128 + lane * 2, acc0 * cinv);
        unsafeAtomicAdd(out + (size_t)curn * 128 + lane * 2 + 1, acc1 * cinv);
        acc0 = 0.f;
        acc1 = 0.f;
        curn = ni;
        cinv = ii;
      }
      unsigned int v = *(const unsigned int*)(hb + i * 272 + lane * 4);
      acc0 += bflo(v);
      acc1 += bfhi(v);
    }
    unsafeAtomicAdd(out + (size_t)curn * 128 + lane * 2, acc0 * cinv);
    unsafeAtomicAdd(out + (size_t)curn * 128 + lane * 2 + 1, acc1 * cinv);
  };

#define LOADRAW(dst, rowv, ev)                              \
  do {                                                      \
    const float* xr_ = x + (size_t)(rowv)*64;               \
    const float* ar_ = ea + (size_t)(ev)*64;                \
    dst[0] = *(const float4*)(xr_ + q * 8);                 \
    dst[1] = *(const float4*)(xr_ + q * 8 + 4);             \
    dst[2] = *(const float4*)(xr_ + 32 + q * 8);            \
    dst[3] = *(const float4*)(xr_ + 32 + q * 8 + 4);        \
    dst[4] = *(const float4*)(ar_ + q * 8);                 \
    dst[5] = *(const float4*)(ar_ + q * 8 + 4);             \
    dst[6] = *(const float4*)(ar_ + 32 + q * 8);            \
    dst[7] = *(const float4*)(ar_ + 32 + q * 8 + 4);        \
  } while (0)

  if constexpr (!ATOMIC) {
    int tA = wid;
    if (tA >= ntiles) return;
    // prologue: idx/node/deg for tiles A and B, raw for tile A
    int pA = tA * 16 + e15;
    int eA = perm[pA];
    int rowA = eidx[eA];
    int ndA = eidx[E + eA];
    float invA = 1.f / (float)cnt[ndA];
    int tB = tA + nwav;
    int tBc = (tB < ntiles) ? tB : tA;
    int pB = tBc * 16 + e15;
    int eB = perm[pB];
    int rowB = eidx[eB];
    int ndB = eidx[E + eB];
    float invB = 1.f / (float)cnt[ndB];
    float4 rawA[8], rawB[8];
    LOADRAW(rawA, rowA, eA);

    for (int tb = tA; tb < ntiles; tb += 2 * nwav) {
      // ---- phase A: compute tile tb; prefetch rawB(tb+nwav), idxA(tb+2nwav)
      {
        int tn = tb + 2 * nwav;
        int tc = (tn < ntiles) ? tn : tb;
        int pn = tc * 16 + e15;
        int eAn = perm[pn];
        int rAn = eidx[eAn];
        int nAn = eidx[E + eAn];
        float iAn = 1.f / (float)cnt[nAn];
        LOADRAW(rawB, rowB, eB);
        f32x4 c2[8];
        mlp_core(rawA, c2);
        reduce_store(c2, ndA, invA);
        eA = eAn;
        rowA = rAn;
        ndA = nAn;
        invA = iAn;
      }
      // ---- phase B: compute tile tb+nwav; prefetch rawA(tb+2nwav), idxB(tb+3nwav)
      {
        int tcur = tb + nwav;
        int tn = tb + 3 * nwav;
        int tc = (tn < ntiles) ? tn : tb;
        int pn = tc * 16 + e15;
        int eBn = perm[pn];
        int rBn = eidx[eBn];
        int nBn = eidx[E + eBn];
        float iBn = 1.f / (float)cnt[nBn];
        LOADRAW(rawA, rowA, eA);
        if (tcur < ntiles) {
          f32x4 c2[8];
          mlp_core(rawB, c2);
          reduce_store(c2, ndB, invB);
        }
        eB = eBn;
        rowB = rBn;
        ndB = nBn;
        invB = iBn;
      }
    }
  } else {
    // fallback: fused atomic scatter of UNSCALED sums (divide_kernel follows)
    for (int t = wid; t < ntiles; t += nwav) {
      const int pos = t * 16 + e15;
      const int e = pos;
      const int row = eidx[e];
      const int cl = eidx[E + e];
      float4 raw[8];
      LOADRAW(raw, row, e);
      f32x4 c2[8];
      mlp_core(raw, c2);
      float* op = out + (size_t)cl * 128 + q * 4;
#pragma unroll
      for (int mt = 0; mt < 8; ++mt)
#pragma unroll
        for (int r = 0; r < 4; ++r) unsafeAtomicAdd(op + mt * 16 + r, c2[mt][r]);
    }
  }
#undef LOADRAW
}

// ------------------------------------------------------ divide (atomic path)
__global__ void divide_kernel(float* __restrict__ out, const int* __restrict__ cnt, int N) {
  int i = blockIdx.x * blockDim.x + threadIdx.x;
  if (i >= N * 32) return;  // N*128/4 float4s
  int node = i >> 5;
  float s = 1.f / (float)(cnt[node] > 0 ? cnt[node] : 1);
  float4* p = (float4*)out + i;
  float4 v = *p;
  v.x *= s;
  v.y *= s;
  v.z *= s;
  v.w *= s;
  *p = v;
}

extern "C" void kernel_launch(void* const* d_in, const int* in_sizes, int n_in,
                              void* d_out, int out_size, void* d_ws, size_t ws_size,
                              hipStream_t stream) {
  const float* x = (const float*)d_in[0];
  const float* ea = (const float*)d_in[1];
  const int* eidx = (const int*)d_in[2];
  const float* W1 = (const float*)d_in[3];
  const float* b1 = (const float*)d_in[4];
  const float* lng = (const float*)d_in[5];
  const float* lnb = (const float*)d_in[6];
  const float* W2 = (const float*)d_in[7];
  const float* b2 = (const float*)d_in[8];
  float* out = (float*)d_out;

  const int N = in_sizes[0] / 64;   // 50000
  const int E = in_sizes[1] / 64;   // 800000
  const int ntiles = E / 16;
  const size_t permB = (size_t)E * 4;
  const size_t cB = (size_t)N * 4;
  const size_t need = permB + 3 * cB;  // perm + cnt/cur/off
  const int eblocks = (E + 255) / 256;

  if (ws_size >= need) {
    // ---- CSR + fused segmented-mean path ----
    int* perm = (int*)d_ws;
    int* cnt = perm + E;
    int* cur = cnt + N;
    int* off = cur + N;
    hipMemsetAsync(out, 0, (size_t)out_size * 4, stream);
    hipMemsetAsync(cnt, 0, 2 * cB, stream);  // cnt + cur contiguous
    hist_kernel<<<eblocks, 256, 0, stream>>>(eidx, cnt, E);
    scan_kernel<<<1, 1024, 0, stream>>>(cnt, off, N);
    scatter_kernel<<<eblocks, 256, 0, stream>>>(eidx, off, cur, perm, E);
    mlp_kernel<false><<<256, 1024, 0, stream>>>(x, ea, eidx, perm, cnt, W1, b1,
                                                lng, lnb, W2, b2, out, E, ntiles);
  } else {
    // ---- fallback: fused atomic scatter (needs only N*4 bytes of ws) ----
    int* cnt = (int*)d_ws;
    hipMemsetAsync(out, 0, (size_t)out_size * 4, stream);
    hipMemsetAsync(cnt, 0, cB, stream);
    hist_kernel<<<eblocks, 256, 0, stream>>>(eidx, cnt, E);
    mlp_kernel<true><<<256, 1024, 0, stream>>>(x, ea, eidx, nullptr, cnt, W1, b1,
                                               lng, lnb, W2, b2, out, E, ntiles);
    divide_kernel<<<(N * 32 + 255) / 256, 256, 0, stream>>>(out, cnt, N);
  }
}